// Round 6
// baseline (605.254 us; speedup 1.0000x reference)
//
#include <hip/hip_runtime.h>

#define N 4096
#define OUTW 12288   // n_x + n_e + n_i

// ---- Kernel A: compact spike indices per input row (ordered) + sx copy ----
__global__ void compact_spikes(const float* __restrict__ X, int* __restrict__ idx,
                               int* __restrict__ cnt, float* __restrict__ out, int T) {
    int t = blockIdx.x;
    const float* row = X + (size_t)t * N;
    __shared__ int counts[256];
    int tid = threadIdx.x;
    int base = tid * 16;
    float4 r0 = *(const float4*)(row + base);
    float4 r1 = *(const float4*)(row + base + 4);
    float4 r2 = *(const float4*)(row + base + 8);
    float4 r3 = *(const float4*)(row + base + 12);
    float* orow = out + (size_t)t * OUTW + base;   // fused sx copy
    *(float4*)(orow)      = r0;
    *(float4*)(orow + 4)  = r1;
    *(float4*)(orow + 8)  = r2;
    *(float4*)(orow + 12) = r3;
    float vals[16];
    *(float4*)(vals)      = r0;
    *(float4*)(vals + 4)  = r1;
    *(float4*)(vals + 8)  = r2;
    *(float4*)(vals + 12) = r3;
    int ks[16];
    int c = 0;
    #pragma unroll
    for (int q = 0; q < 16; ++q) {
        if (vals[q] != 0.0f) ks[c++] = base + q;
    }
    counts[tid] = c;
    __syncthreads();
    int off = 0;
    for (int i = 0; i < tid; ++i) off += counts[i];
    int* op = idx + (size_t)t * N;
    for (int q = 0; q < c; ++q) op[off + q] = ks[q];
    if (tid == 255) cnt[t] = off + c;
}

// ---- Kernel B: XW[t] = X[t-1] @ W via sparse row-gather (ascending order) --
__global__ void gather_xw(const float* __restrict__ W, const int* __restrict__ idx,
                          const int* __restrict__ cnt, float* __restrict__ XW) {
    int b = blockIdx.x;
    int t = b >> 2;
    int tile = b & 3;
    int col = tile * 1024 + threadIdx.x * 4;
    float4 acc = {0.f, 0.f, 0.f, 0.f};
    if (t > 0) {
        int r = t - 1;
        int c = cnt[r];
        const int* ip = idx + (size_t)r * N;
        __shared__ int sidx[4096];
        for (int s = threadIdx.x; s < c; s += blockDim.x) sidx[s] = ip[s];
        __syncthreads();
        int s = 0;
        for (; s + 4 <= c; s += 4) {
            int k0 = sidx[s], k1 = sidx[s + 1], k2 = sidx[s + 2], k3 = sidx[s + 3];
            float4 w0 = *(const float4*)(W + (size_t)k0 * N + col);
            float4 w1 = *(const float4*)(W + (size_t)k1 * N + col);
            float4 w2 = *(const float4*)(W + (size_t)k2 * N + col);
            float4 w3 = *(const float4*)(W + (size_t)k3 * N + col);
            acc.x += w0.x; acc.y += w0.y; acc.z += w0.z; acc.w += w0.w;
            acc.x += w1.x; acc.y += w1.y; acc.z += w1.z; acc.w += w1.w;
            acc.x += w2.x; acc.y += w2.y; acc.z += w2.z; acc.w += w2.w;
            acc.x += w3.x; acc.y += w3.y; acc.z += w3.z; acc.w += w3.w;
        }
        for (; s < c; ++s) {
            int k = sidx[s];
            float4 w0 = *(const float4*)(W + (size_t)k * N + col);
            acc.x += w0.x; acc.y += w0.y; acc.z += w0.z; acc.w += w0.w;
        }
    }
    *(float4*)(XW + (size_t)t * N + col) = acc;
}

// ---- Kernel C: sequential LIF recurrence, single block of 256 threads ------
// 16 e + 16 i neurons per thread (fixed overhead amortized 4x vs round 5).
// i-neurons: 4 SWAR u32s of refractory bytes (exact shortcut, round-2 proof).
// e-phase float expressions identical to the verified round-3/5 forms.
// S count: SWAR byte-sum -> horizontal mul -> 6-level shfl_xor int reduce
// (exact) -> one LDS atomicAdd per wave; cS[3] triple-buffer, static parity.
__global__ void __launch_bounds__(256)
recurrent(const float* __restrict__ XW, unsigned char* __restrict__ pk, int T) {
    const int tid = threadIdx.x;     // 0..255
    const int lane = tid & 63;
    __shared__ unsigned int cS[3];
    if (tid < 3) cS[tid] = 0u;

    float ve[16], ref[16], si_f[16];
    unsigned int R[4] = {0u, 0u, 0u, 0u};   // i-refractory bytes {0,1,2}
    unsigned int E[4] = {0u, 0u, 0u, 0u};   // e-spike bytes {0,1}
    #pragma unroll
    for (int q = 0; q < 16; ++q) { ve[q] = -65.0f; ref[q] = 0.0f; si_f[q] = 0.0f; }

    // thread owns neurons [16*tid, 16*tid+16): 4 float4s per XW row
    const float4* xwp = (const float4*)XW + (size_t)tid * 4;   // row stride 1024
    float4 xw0 = xwp[0], xw1 = xwp[1], xw2 = xwp[2], xw3 = xwp[3];  // row 0 = zeros
    unsigned int* pk32 = (unsigned int*)pk + tid;              // row stride 256
    __syncthreads();

    int t = 0;
    #define STEP(PAR)                                                          \
    {                                                                          \
        unsigned int Sint = cS[(PAR + 2) % 3];   /* S(t-1), broadcast read */  \
        float4 n0 = xw0, n1 = xw1, n2 = xw2, n3 = xw3;                         \
        if (t + 1 < T) {                                                       \
            const float4* p = xwp + (size_t)(t + 1) * 1024;                    \
            n0 = p[0]; n1 = p[1]; n2 = p[2]; n3 = p[3];                        \
        }                                                                      \
        if (tid == 0) cS[(PAR + 1) % 3] = 0u;    /* counter for step t+1 */    \
        /* i-phase: SWAR over 4 u32 groups (exact shortcut) */                 \
        unsigned int z[4];                                                     \
        _Pragma("unroll")                                                      \
        for (int g = 0; g < 4; ++g) {                                          \
            unsigned int nz = (R[g] | (R[g] >> 1)) & 0x01010101u;              \
            unsigned int zg = (nz ^ 0x01010101u) & E[g];                       \
            R[g] = (R[g] - nz) | (zg << 1);                                    \
            z[g] = zg;                                                         \
        }                                                                      \
        /* exact spike count: bytes <=4, horizontal sum <=16 */                \
        unsigned int zsum = (z[0] + z[1]) + (z[2] + z[3]);                     \
        int tot = (int)((zsum * 0x01010101u) >> 24);                           \
        tot += __shfl_xor(tot, 1, 64);                                         \
        tot += __shfl_xor(tot, 2, 64);                                         \
        tot += __shfl_xor(tot, 4, 64);                                         \
        tot += __shfl_xor(tot, 8, 64);                                         \
        tot += __shfl_xor(tot, 16, 64);                                        \
        tot += __shfl_xor(tot, 32, 64);                                        \
        if (lane == 0) atomicAdd(&cS[PAR], (unsigned int)tot);                 \
        /* e-phase: float exprs match verified rounds 3/5 */                   \
        float Sf = (float)Sint;                                                \
        float xq[16];                                                          \
        *(float4*)(xq)      = xw0;                                             \
        *(float4*)(xq + 4)  = xw1;                                             \
        *(float4*)(xq + 8)  = xw2;                                             \
        *(float4*)(xq + 12) = xw3;                                             \
        unsigned int sbits = 0u;                                               \
        _Pragma("unroll")                                                      \
        for (int q = 0; q < 16; ++q) {                                         \
            float dS = Sf - si_f[q];                       /* exact int diff */\
            float in_e = xq[q] - 17.5f * dS;               /* exact product  */\
            float in_sel = (ref[q] <= 0.0f) ? in_e : 0.0f;                     \
            float v = ve[q] + 0.01f * (-65.0f - ve[q]) + in_sel;               \
            float rc = fmaxf(ref[q] - 1.0f, 0.0f);                             \
            int s = (v >= -52.0f) ? 1 : 0;                                     \
            ref[q] = s ? 5.0f : rc;                                            \
            ve[q]  = s ? -65.0f : v;                                           \
            sbits |= (unsigned int)s << q;                                     \
        }                                                                      \
        /* E bytes from sbits nibbles (verified bit-spread trick) */           \
        _Pragma("unroll")                                                      \
        for (int g = 0; g < 4; ++g)                                            \
            E[g] = (((sbits >> (4 * g)) & 0xFu) * 0x00204081u) & 0x01010101u;  \
        /* si_f for next step */                                               \
        _Pragma("unroll")                                                      \
        for (int q = 0; q < 16; ++q)                                           \
            si_f[q] = (float)((z[q >> 2] >> ((q & 3) * 8)) & 1u);              \
        /* pack output word: byte j = se nibble j | si nibble j << 4 */        \
        unsigned int xsp = sbits;                                              \
        xsp = (xsp | (xsp << 8)) & 0x00FF00FFu;                                \
        xsp = (xsp | (xsp << 4)) & 0x0F0F0F0Fu;   /* nibbles -> byte lanes */  \
        unsigned int w = xsp;                                                  \
        _Pragma("unroll")                                                      \
        for (int g = 0; g < 4; ++g)                                            \
            w |= ((z[g] * 0x10204080u) >> 24) << (8 * g);  /* si bits 4..7 */  \
        if (t < T) pk32[(size_t)t * 256] = w;                                  \
        xw0 = n0; xw1 = n1; xw2 = n2; xw3 = n3;                                \
        __syncthreads();                                                       \
        ++t;                                                                   \
    }

    for (int u = 0; u < 167; ++u) {  // 501 steps; step 500 is a guarded no-op
        STEP(0)
        STEP(1)
        STEP(2)
    }
    #undef STEP
}

// ---- Kernel E: expand packed spike bits -> f32 output ----------------------
__global__ void expand(const unsigned char* __restrict__ pk, float* __restrict__ out, int T) {
    int i = blockIdx.x * 256 + threadIdx.x;   // [0, T*1024)
    if (i >= T * 1024) return;
    int t = i >> 10;
    int g = i & 1023;
    unsigned int b = pk[i];
    float* orow = out + (size_t)t * OUTW + N + (size_t)g * 4;
    float4 se4 = {(float)(b & 1u), (float)((b >> 1) & 1u),
                  (float)((b >> 2) & 1u), (float)((b >> 3) & 1u)};
    float4 si4 = {(float)((b >> 4) & 1u), (float)((b >> 5) & 1u),
                  (float)((b >> 6) & 1u), (float)((b >> 7) & 1u)};
    *(float4*)orow = se4;
    *(float4*)(orow + N) = si4;
}

extern "C" void kernel_launch(void* const* d_in, const int* in_sizes, int n_in,
                              void* d_out, int out_size, void* d_ws, size_t ws_size,
                              hipStream_t stream) {
    const float* X   = (const float*)d_in[0];   // [T, 4096]
    const float* Wxe = (const float*)d_in[1];   // [4096, 4096]
    int T = in_sizes[0] / N;
    float* out = (float*)d_out;

    // ws layout (proven in rounds 1-3/5):
    //   XW  float[T*N] @ 0
    //   idx int[T*N]   @ T*N*4   (pk overlays idx; idx dead after gather_xw)
    //   cnt int[T]     @ 2*T*N*4
    float* XW = (float*)d_ws;
    int* idx  = (int*)((char*)d_ws + (size_t)T * N * 4);
    int* cnt  = (int*)((char*)d_ws + (size_t)2 * T * N * 4);
    unsigned char* pk = (unsigned char*)idx;

    compact_spikes<<<T, 256, 0, stream>>>(X, idx, cnt, out, T);
    gather_xw<<<T * 4, 256, 0, stream>>>(Wxe, idx, cnt, XW);
    recurrent<<<1, 256, 0, stream>>>(XW, pk, T);
    expand<<<(T * 1024 + 255) / 256, 256, 0, stream>>>(pk, out, T);
}

// Round 8
// 538.831 us; speedup vs baseline: 1.1233x; 1.1233x over previous
//
#include <hip/hip_runtime.h>

#define N 4096
#define OUTW 12288   // n_x + n_e + n_i

// ---- Kernel A: compact spike indices per input row (ordered) + sx copy ----
__global__ void compact_spikes(const float* __restrict__ X, int* __restrict__ idx,
                               int* __restrict__ cnt, float* __restrict__ out, int T) {
    int t = blockIdx.x;
    const float* row = X + (size_t)t * N;
    __shared__ int counts[256];
    int tid = threadIdx.x;
    int base = tid * 16;
    float4 r0 = *(const float4*)(row + base);
    float4 r1 = *(const float4*)(row + base + 4);
    float4 r2 = *(const float4*)(row + base + 8);
    float4 r3 = *(const float4*)(row + base + 12);
    float* orow = out + (size_t)t * OUTW + base;   // fused sx copy
    *(float4*)(orow)      = r0;
    *(float4*)(orow + 4)  = r1;
    *(float4*)(orow + 8)  = r2;
    *(float4*)(orow + 12) = r3;
    float vals[16];
    *(float4*)(vals)      = r0;
    *(float4*)(vals + 4)  = r1;
    *(float4*)(vals + 8)  = r2;
    *(float4*)(vals + 12) = r3;
    int ks[16];
    int c = 0;
    #pragma unroll
    for (int q = 0; q < 16; ++q) {
        if (vals[q] != 0.0f) ks[c++] = base + q;
    }
    counts[tid] = c;
    __syncthreads();
    int off = 0;
    for (int i = 0; i < tid; ++i) off += counts[i];
    int* op = idx + (size_t)t * N;
    for (int q = 0; q < c; ++q) op[off + q] = ks[q];
    if (tid == 255) cnt[t] = off + c;
}

// ---- Kernel B: XW[t] = X[t-1] @ W via sparse row-gather (ascending order) --
__global__ void gather_xw(const float* __restrict__ W, const int* __restrict__ idx,
                          const int* __restrict__ cnt, float* __restrict__ XW) {
    int b = blockIdx.x;
    int t = b >> 2;
    int tile = b & 3;
    int col = tile * 1024 + threadIdx.x * 4;
    float4 acc = {0.f, 0.f, 0.f, 0.f};
    if (t > 0) {
        int r = t - 1;
        int c = cnt[r];
        const int* ip = idx + (size_t)r * N;
        __shared__ int sidx[4096];
        for (int s = threadIdx.x; s < c; s += blockDim.x) sidx[s] = ip[s];
        __syncthreads();
        int s = 0;
        for (; s + 4 <= c; s += 4) {
            int k0 = sidx[s], k1 = sidx[s + 1], k2 = sidx[s + 2], k3 = sidx[s + 3];
            float4 w0 = *(const float4*)(W + (size_t)k0 * N + col);
            float4 w1 = *(const float4*)(W + (size_t)k1 * N + col);
            float4 w2 = *(const float4*)(W + (size_t)k2 * N + col);
            float4 w3 = *(const float4*)(W + (size_t)k3 * N + col);
            acc.x += w0.x; acc.y += w0.y; acc.z += w0.z; acc.w += w0.w;
            acc.x += w1.x; acc.y += w1.y; acc.z += w1.z; acc.w += w1.w;
            acc.x += w2.x; acc.y += w2.y; acc.z += w2.z; acc.w += w2.w;
            acc.x += w3.x; acc.y += w3.y; acc.z += w3.z; acc.w += w3.w;
        }
        for (; s < c; ++s) {
            int k = sidx[s];
            float4 w0 = *(const float4*)(W + (size_t)k * N + col);
            acc.x += w0.x; acc.y += w0.y; acc.z += w0.z; acc.w += w0.w;
        }
    }
    *(float4*)(XW + (size_t)t * N + col) = acc;
}

// ---- Kernel C: sequential LIF recurrence, single block of 512 threads ------
// 8 e + 8 i neurons per thread; 2 waves/SIMD. i-neurons: 2 SWAR u32s of
// refractory bytes (exact shortcut, round-2 proof). e-phase float expressions
// identical to the verified round-3/5 forms. Pack fix vs round 7: the si
// nibble from (z*0x10204080)>>24 is ALREADY at bits 4..7 — OR it directly
// (byte 0) / <<8 (byte 1); no extra <<4.
__global__ void __launch_bounds__(512)
recurrent(const float* __restrict__ XW, unsigned char* __restrict__ pk, int T) {
    const int tid = threadIdx.x;     // 0..511
    const int lane = tid & 63;
    __shared__ unsigned int cS[3];
    if (tid < 3) cS[tid] = 0u;

    float ve[8], ref[8], si_f[8];
    unsigned int R[2] = {0u, 0u};   // i-refractory bytes {0,1,2}
    unsigned int E[2] = {0u, 0u};   // e-spike bytes {0,1}
    #pragma unroll
    for (int q = 0; q < 8; ++q) { ve[q] = -65.0f; ref[q] = 0.0f; si_f[q] = 0.0f; }

    // thread owns neurons [8*tid, 8*tid+8): 2 float4s per XW row
    const float4* xwp = (const float4*)XW + (size_t)tid * 2;   // row stride 1024
    float4 xwA = xwp[0], xwB = xwp[1];                         // row 0 = zeros
    unsigned short* pk16 = (unsigned short*)pk + tid;          // row stride 512
    __syncthreads();

    int t = 0;
    #define STEP(PAR)                                                          \
    {                                                                          \
        unsigned int Sint = cS[(PAR + 2) % 3];   /* S(t-1), broadcast read */  \
        float4 nA = xwA, nB = xwB;                                             \
        if (t + 1 < T) {                                                       \
            const float4* p = xwp + (size_t)(t + 1) * 1024;                    \
            nA = p[0]; nB = p[1];                                              \
        }                                                                      \
        if (tid == 0) cS[(PAR + 1) % 3] = 0u;    /* counter for step t+1 */    \
        /* i-phase: SWAR over 2 u32 groups (exact shortcut) */                 \
        unsigned int z[2];                                                     \
        _Pragma("unroll")                                                      \
        for (int g = 0; g < 2; ++g) {                                          \
            unsigned int nz = (R[g] | (R[g] >> 1)) & 0x01010101u;              \
            unsigned int zg = (nz ^ 0x01010101u) & E[g];                       \
            R[g] = (R[g] - nz) | (zg << 1);                                    \
            z[g] = zg;                                                         \
        }                                                                      \
        /* exact spike count: bytes <=2, horizontal sum <=8 */                 \
        unsigned int zsum = z[0] + z[1];                                       \
        int tot = (int)((zsum * 0x01010101u) >> 24);                           \
        tot += __shfl_xor(tot, 1, 64);                                         \
        tot += __shfl_xor(tot, 2, 64);                                         \
        tot += __shfl_xor(tot, 4, 64);                                         \
        tot += __shfl_xor(tot, 8, 64);                                         \
        tot += __shfl_xor(tot, 16, 64);                                        \
        tot += __shfl_xor(tot, 32, 64);                                        \
        if (lane == 0) atomicAdd(&cS[PAR], (unsigned int)tot);                 \
        /* e-phase: float exprs match verified rounds 3/5 */                   \
        float Sf = (float)Sint;                                                \
        float xq[8];                                                           \
        *(float4*)(xq)     = xwA;                                              \
        *(float4*)(xq + 4) = xwB;                                              \
        unsigned int sbits = 0u;                                               \
        _Pragma("unroll")                                                      \
        for (int q = 0; q < 8; ++q) {                                          \
            float dS = Sf - si_f[q];                       /* exact int diff */\
            float in_e = xq[q] - 17.5f * dS;               /* exact product  */\
            float in_sel = (ref[q] <= 0.0f) ? in_e : 0.0f;                     \
            float v = ve[q] + 0.01f * (-65.0f - ve[q]) + in_sel;               \
            float rc = fmaxf(ref[q] - 1.0f, 0.0f);                             \
            int s = (v >= -52.0f) ? 1 : 0;                                     \
            ref[q] = s ? 5.0f : rc;                                            \
            ve[q]  = s ? -65.0f : v;                                           \
            sbits |= (unsigned int)s << q;                                     \
        }                                                                      \
        /* E bytes from sbits nibbles (verified bit-spread trick) */           \
        E[0] = ((sbits & 0xFu)        * 0x00204081u) & 0x01010101u;            \
        E[1] = (((sbits >> 4) & 0xFu) * 0x00204081u) & 0x01010101u;            \
        /* si_f for next step */                                               \
        _Pragma("unroll")                                                      \
        for (int q = 0; q < 8; ++q)                                            \
            si_f[q] = (float)((z[q >> 2] >> ((q & 3) * 8)) & 1u);              \
        /* pack halfword: byte g = se nibble g (bits 0..3) | si nibble g   */  \
        /* (bits 4..7). znib from the mul-trick is ALREADY at bits 4..7.   */  \
        unsigned int w = (sbits | (sbits << 4)) & 0x0F0Fu;                     \
        w |= ((z[0] * 0x10204080u) >> 24);                                     \
        w |= (((z[1] * 0x10204080u) >> 24) << 8);                              \
        if (t < T) pk16[(size_t)t * 512] = (unsigned short)w;                  \
        xwA = nA; xwB = nB;                                                    \
        __syncthreads();                                                       \
        ++t;                                                                   \
    }

    for (int u = 0; u < 167; ++u) {  // 501 steps; step 500 is a guarded no-op
        STEP(0)
        STEP(1)
        STEP(2)
    }
    #undef STEP
}

// ---- Kernel E: expand packed spike bits -> f32 output ----------------------
__global__ void expand(const unsigned char* __restrict__ pk, float* __restrict__ out, int T) {
    int i = blockIdx.x * 256 + threadIdx.x;   // [0, T*1024)
    if (i >= T * 1024) return;
    int t = i >> 10;
    int g = i & 1023;
    unsigned int b = pk[i];
    float* orow = out + (size_t)t * OUTW + N + (size_t)g * 4;
    float4 se4 = {(float)(b & 1u), (float)((b >> 1) & 1u),
                  (float)((b >> 2) & 1u), (float)((b >> 3) & 1u)};
    float4 si4 = {(float)((b >> 4) & 1u), (float)((b >> 5) & 1u),
                  (float)((b >> 6) & 1u), (float)((b >> 7) & 1u)};
    *(float4*)orow = se4;
    *(float4*)(orow + N) = si4;
}

extern "C" void kernel_launch(void* const* d_in, const int* in_sizes, int n_in,
                              void* d_out, int out_size, void* d_ws, size_t ws_size,
                              hipStream_t stream) {
    const float* X   = (const float*)d_in[0];   // [T, 4096]
    const float* Wxe = (const float*)d_in[1];   // [4096, 4096]
    int T = in_sizes[0] / N;
    float* out = (float*)d_out;

    // ws layout (proven in rounds 1-3/5):
    //   XW  float[T*N] @ 0
    //   idx int[T*N]   @ T*N*4   (pk overlays idx; idx dead after gather_xw)
    //   cnt int[T]     @ 2*T*N*4
    float* XW = (float*)d_ws;
    int* idx  = (int*)((char*)d_ws + (size_t)T * N * 4);
    int* cnt  = (int*)((char*)d_ws + (size_t)2 * T * N * 4);
    unsigned char* pk = (unsigned char*)idx;

    compact_spikes<<<T, 256, 0, stream>>>(X, idx, cnt, out, T);
    gather_xw<<<T * 4, 256, 0, stream>>>(Wxe, idx, cnt, XW);
    recurrent<<<1, 512, 0, stream>>>(XW, pk, T);
    expand<<<(T * 1024 + 255) / 256, 256, 0, stream>>>(pk, out, T);
}

// Round 9
// 467.849 us; speedup vs baseline: 1.2937x; 1.1517x over previous
//
#include <hip/hip_runtime.h>

#define N 4096
#define OUTW 12288   // n_x + n_e + n_i

// ---- Kernel A: compact spike indices per input row (ordered) + sx copy ----
__global__ void compact_spikes(const float* __restrict__ X, int* __restrict__ idx,
                               int* __restrict__ cnt, float* __restrict__ out, int T) {
    int t = blockIdx.x;
    const float* row = X + (size_t)t * N;
    __shared__ int counts[256];
    int tid = threadIdx.x;
    int base = tid * 16;
    float4 r0 = *(const float4*)(row + base);
    float4 r1 = *(const float4*)(row + base + 4);
    float4 r2 = *(const float4*)(row + base + 8);
    float4 r3 = *(const float4*)(row + base + 12);
    float* orow = out + (size_t)t * OUTW + base;   // fused sx copy
    *(float4*)(orow)      = r0;
    *(float4*)(orow + 4)  = r1;
    *(float4*)(orow + 8)  = r2;
    *(float4*)(orow + 12) = r3;
    float vals[16];
    *(float4*)(vals)      = r0;
    *(float4*)(vals + 4)  = r1;
    *(float4*)(vals + 8)  = r2;
    *(float4*)(vals + 12) = r3;
    int ks[16];
    int c = 0;
    #pragma unroll
    for (int q = 0; q < 16; ++q) {
        if (vals[q] != 0.0f) ks[c++] = base + q;
    }
    counts[tid] = c;
    __syncthreads();
    int off = 0;
    for (int i = 0; i < tid; ++i) off += counts[i];
    int* op = idx + (size_t)t * N;
    for (int q = 0; q < c; ++q) op[off + q] = ks[q];
    if (tid == 255) cnt[t] = off + c;
}

// ---- Kernel B: XW[t] = X[t-1] @ W via sparse row-gather (ascending order) --
__global__ void gather_xw(const float* __restrict__ W, const int* __restrict__ idx,
                          const int* __restrict__ cnt, float* __restrict__ XW) {
    int b = blockIdx.x;
    int t = b >> 2;
    int tile = b & 3;
    int col = tile * 1024 + threadIdx.x * 4;
    float4 acc = {0.f, 0.f, 0.f, 0.f};
    if (t > 0) {
        int r = t - 1;
        int c = cnt[r];
        const int* ip = idx + (size_t)r * N;
        __shared__ int sidx[4096];
        for (int s = threadIdx.x; s < c; s += blockDim.x) sidx[s] = ip[s];
        __syncthreads();
        int s = 0;
        for (; s + 4 <= c; s += 4) {
            int k0 = sidx[s], k1 = sidx[s + 1], k2 = sidx[s + 2], k3 = sidx[s + 3];
            float4 w0 = *(const float4*)(W + (size_t)k0 * N + col);
            float4 w1 = *(const float4*)(W + (size_t)k1 * N + col);
            float4 w2 = *(const float4*)(W + (size_t)k2 * N + col);
            float4 w3 = *(const float4*)(W + (size_t)k3 * N + col);
            acc.x += w0.x; acc.y += w0.y; acc.z += w0.z; acc.w += w0.w;
            acc.x += w1.x; acc.y += w1.y; acc.z += w1.z; acc.w += w1.w;
            acc.x += w2.x; acc.y += w2.y; acc.z += w2.z; acc.w += w2.w;
            acc.x += w3.x; acc.y += w3.y; acc.z += w3.z; acc.w += w3.w;
        }
        for (; s < c; ++s) {
            int k = sidx[s];
            float4 w0 = *(const float4*)(W + (size_t)k * N + col);
            acc.x += w0.x; acc.y += w0.y; acc.z += w0.z; acc.w += w0.w;
        }
    }
    *(float4*)(XW + (size_t)t * N + col) = acc;
}

// ---- Kernel C: sequential LIF recurrence, single block of 1024 threads -----
// 4 e + 4 i neurons/thread (round-5 verified config: max waves hide latency).
// Changes vs round 5: (1) pk store DEFERRED past the barrier (held in a reg,
// stored at the start of the next step) so __syncthreads' vmcnt(0) drain no
// longer waits on a just-issued global store; (2) si_f float array replaced
// by dS = bit ? Sf-1 : Sf (cndmask; bitwise-identical since Sf and Sf-1 are
// exact small integers). All spike-deciding float exprs keep verified forms.
__global__ void __launch_bounds__(1024)
recurrent(const float* __restrict__ XW, unsigned char* __restrict__ pk, int T) {
    const int tid = threadIdx.x;
    const int lane = tid & 63;
    __shared__ unsigned int cS[3];
    if (tid < 3) cS[tid] = 0u;

    float ve[4], ref[4];
    unsigned int R = 0u;    // i-refractory bytes {0,1,2}
    unsigned int E = 0u;    // e-spike bytes {0,1} (from previous step)
    unsigned int zp = 0u;   // i-spike bytes from previous step (s_i(t-1))
    unsigned char pw = 0;   // pending pk word (previous step's spikes)
    #pragma unroll
    for (int q = 0; q < 4; ++q) { ve[q] = -65.0f; ref[q] = 0.0f; }

    const float4* xwp = (const float4*)XW + tid;   // row stride 1024 float4s
    float4 xw = xwp[0];                            // row 0 (zeros)
    unsigned char* pkp = pk + tid;
    __syncthreads();

    int t = 0;
    #define STEP(PAR)                                                          \
    {                                                                          \
        unsigned int Sint = cS[(PAR + 2) % 3];   /* S(t-1), broadcast read */  \
        if (t > 0) pkp[(size_t)(t - 1) * 1024] = pw;  /* deferred store */     \
        float4 xw_n = xw;                                                      \
        if (t + 1 < T) xw_n = xwp[(size_t)(t + 1) * 1024];                     \
        if (tid == 0) cS[(PAR + 1) % 3] = 0u;    /* counter for step t+1 */    \
        /* i-phase: SWAR over 4 byte-lanes (exact shortcut, round-2 proof) */  \
        unsigned int nz = (R | (R >> 1)) & 0x01010101u;                        \
        unsigned int z  = (nz ^ 0x01010101u) & E;                              \
        R = (R - nz) | (z << 1);                                               \
        int c0 = __popcll(__ballot((z & 0x000000ffu) != 0u));                  \
        int c1 = __popcll(__ballot((z & 0x0000ff00u) != 0u));                  \
        int c2 = __popcll(__ballot((z & 0x00ff0000u) != 0u));                  \
        int c3 = __popcll(__ballot((z & 0xff000000u) != 0u));                  \
        if (lane == 0) atomicAdd(&cS[PAR], (unsigned int)(c0 + c1 + c2 + c3)); \
        /* e-phase: float exprs match verified rounds 3/5 */                   \
        float Sf  = (float)Sint;                                               \
        float Sf1 = Sf - 1.0f;                   /* exact integer */           \
        const float xq[4] = {xw.x, xw.y, xw.z, xw.w};                          \
        unsigned int sbits = 0u;                                               \
        _Pragma("unroll")                                                      \
        for (int q = 0; q < 4; ++q) {                                          \
            unsigned int bq = (zp >> (q * 8)) & 1u;    /* s_i(t-1) bit */      \
            float dS = bq ? Sf1 : Sf;      /* == Sf - si_f[q], bit-exact */    \
            float in_e = xq[q] - 17.5f * dS;               /* exact product */ \
            float in_sel = (ref[q] <= 0.0f) ? in_e : 0.0f;                     \
            float v = ve[q] + 0.01f * (-65.0f - ve[q]) + in_sel;               \
            float rc = fmaxf(ref[q] - 1.0f, 0.0f);                             \
            int s = (v >= -52.0f) ? 1 : 0;                                     \
            ref[q] = s ? 5.0f : rc;                                            \
            ve[q]  = s ? -65.0f : v;                                           \
            sbits |= (unsigned int)s << q;                                     \
        }                                                                      \
        E = (sbits * 0x00204081u) & 0x01010101u;     /* bits0..3 -> bytes */   \
        unsigned int znib = (z * 0x10204080u) >> 24; /* bytes -> bits4..7 */   \
        pw = (unsigned char)(sbits | znib);                                    \
        zp = z;                                                                \
        xw = xw_n;                                                             \
        __syncthreads();                                                       \
        ++t;                                                                   \
    }

    for (int u = 0; u < 167; ++u) {  // 501 steps; step 500 computes garbage
        STEP(0)                      // but ITS store writes word 499, and its
        STEP(1)                      // own word is never stored.
        STEP(2)
    }
    #undef STEP
}

// ---- Kernel E: expand packed spike bits -> f32 output ----------------------
__global__ void expand(const unsigned char* __restrict__ pk, float* __restrict__ out, int T) {
    int i = blockIdx.x * 256 + threadIdx.x;   // [0, T*1024)
    if (i >= T * 1024) return;
    int t = i >> 10;
    int g = i & 1023;
    unsigned int b = pk[i];
    float* orow = out + (size_t)t * OUTW + N + (size_t)g * 4;
    float4 se4 = {(float)(b & 1u), (float)((b >> 1) & 1u),
                  (float)((b >> 2) & 1u), (float)((b >> 3) & 1u)};
    float4 si4 = {(float)((b >> 4) & 1u), (float)((b >> 5) & 1u),
                  (float)((b >> 6) & 1u), (float)((b >> 7) & 1u)};
    *(float4*)orow = se4;
    *(float4*)(orow + N) = si4;
}

extern "C" void kernel_launch(void* const* d_in, const int* in_sizes, int n_in,
                              void* d_out, int out_size, void* d_ws, size_t ws_size,
                              hipStream_t stream) {
    const float* X   = (const float*)d_in[0];   // [T, 4096]
    const float* Wxe = (const float*)d_in[1];   // [4096, 4096]
    int T = in_sizes[0] / N;
    float* out = (float*)d_out;

    // ws layout (proven in rounds 1-3/5):
    //   XW  float[T*N] @ 0
    //   idx int[T*N]   @ T*N*4   (pk overlays idx; idx dead after gather_xw)
    //   cnt int[T]     @ 2*T*N*4
    float* XW = (float*)d_ws;
    int* idx  = (int*)((char*)d_ws + (size_t)T * N * 4);
    int* cnt  = (int*)((char*)d_ws + (size_t)2 * T * N * 4);
    unsigned char* pk = (unsigned char*)idx;

    compact_spikes<<<T, 256, 0, stream>>>(X, idx, cnt, out, T);
    gather_xw<<<T * 4, 256, 0, stream>>>(Wxe, idx, cnt, XW);
    recurrent<<<1, 1024, 0, stream>>>(XW, pk, T);
    expand<<<(T * 1024 + 255) / 256, 256, 0, stream>>>(pk, out, T);
}